// Round 3
// baseline (4976.607 us; speedup 1.0000x reference)
//
#include <hip/hip_runtime.h>
#include <cstdint>
#include <cstddef>

#define BS 8
#define TT 256
#define DD 2048
#define NN 8192
#define KK 64
#define GG 512
#define GSZ 16
#define HH 64
#define MIN_ 69
#define MOUT_ 66
#define NSL 32     // slices per batch
#define SLN 256    // neurons per slice

typedef float f32x4 __attribute__((ext_vector_type(4)));

// ---------------- Phase A: modulator (runs once) ----------------
__global__ __launch_bounds__(256) void modulator_kernel(
    const float* __restrict__ w1, const float* __restrict__ b1,
    const float* __restrict__ w2, const float* __restrict__ b2,
    const float* __restrict__ act0, const float* __restrict__ heb0,
    const float* __restrict__ dec0, const float* __restrict__ thr0,
    const float* __restrict__ nid,
    float* __restrict__ wconn, float* __restrict__ decayB, float* __restrict__ thrB)
{
  const int g = blockIdx.x, b = blockIdx.y, tid = threadIdx.x;
  __shared__ float xs[GSZ][MIN_];
  __shared__ float hd[GSZ][HH];

  const int nbase = g * GSZ;
  // mod_in = [act(1), hebbian(64), decay(1), threshold(1), nid(2)]
  for (int j = tid; j < GSZ * KK; j += 256) {
    int s = j >> 6, k = j & 63;
    xs[s][1 + k] = heb0[((size_t)(b * NN + nbase + s)) * KK + k];
  }
  if (tid < GSZ) {
    int n = nbase + tid;
    xs[tid][0]  = act0[b * NN + n];
    xs[tid][65] = dec0[b * NN + n];
    xs[tid][66] = thr0[b * NN + n];
    xs[tid][67] = nid[2 * n];
    xs[tid][68] = nid[2 * n + 1];
  }
  __syncthreads();

  // hdn[s][h] = tanh(sum_i xs[s][i]*w1[g][i][h] + b1[g][h])
  for (int rep = 0; rep < 4; ++rep) {
    int t2 = tid + rep * 256;
    int s = t2 >> 6, h = t2 & 63;
    float acc = b1[g * HH + h];
    const float* w1g = w1 + (size_t)g * MIN_ * HH + h;
    for (int i = 0; i < MIN_; ++i) acc = fmaf(xs[s][i], w1g[(size_t)i * HH], acc);
    hd[s][h] = tanhf(acc);
  }
  __syncthreads();

  // out[s][o] = sum_h hd[s][h]*w2[g][h][o] + b2[g][o]
  for (int j = tid; j < GSZ * MOUT_; j += 256) {
    int s = j / MOUT_, o = j - s * MOUT_;
    float acc = b2[g * MOUT_ + o];
    const float* w2g = w2 + (size_t)g * HH * MOUT_ + o;
    for (int h = 0; h < HH; ++h) acc = fmaf(hd[s][h], w2g[(size_t)h * MOUT_], acc);
    int gidx = b * NN + nbase + s;
    if (o < KK)       wconn[(size_t)gidx * KK + o] = acc;
    else if (o == KK) decayB[gidx] = 1.f / (1.f + expf(-acc));
    else              thrB[gidx]   = acc;
  }
}

// ---------------- Phase B: 256-step recurrent scan ----------------
// 256 WGs (8 batches x 32 slices), 256 threads, 1 neuron/thread.
// Exchange via coherent (sc0 sc1) accesses: no cache maintenance ever.
// Order: act store -> vmcnt(0) -> syncthreads -> counter add.
// Readers: poll counter >= 32*(t+1) -> batched vectorized sc0sc1 reload.
// WAR safety (double buffer): a WG publishes into buffer pw at step t+2 only
// after poll(t+1) passed, i.e. all slices incremented at t+1, which is ordered
// after their step-t reload completed (their vmcnt(0) covers those loads).
__global__ __launch_bounds__(256, 1) void scan_kernel(
    const float* __restrict__ cc, const int* __restrict__ conn,
    const float* __restrict__ V0, const float* __restrict__ act0,
    const float* __restrict__ wconn, const float* __restrict__ decayB,
    const float* __restrict__ thrB,
    float* __restrict__ out, float* actbuf, int* cnt)
{
  const int tid = threadIdx.x;
  const int b  = blockIdx.x >> 5;
  const int sl = blockIdx.x & 31;
  const int n    = sl * SLN + tid;
  const int gidx = b * NN + n;

  __shared__ float alds[NN];   // 32 KB: full act of batch b

  // persistent per-thread state
  float w[KK];
  int   ad[KK];
  {
    const float4* wr = reinterpret_cast<const float4*>(wconn + (size_t)gidx * KK);
    #pragma unroll
    for (int j = 0; j < KK / 4; ++j) {
      float4 v = wr[j];
      w[4*j+0] = v.x; w[4*j+1] = v.y; w[4*j+2] = v.z; w[4*j+3] = v.w;
    }
    const int4* ir = reinterpret_cast<const int4*>(conn + (size_t)n * KK);
    #pragma unroll
    for (int j = 0; j < KK / 4; ++j) {
      int4 v = ir[j];
      ad[4*j+0] = v.x; ad[4*j+1] = v.y; ad[4*j+2] = v.z; ad[4*j+3] = v.w;
    }
  }
  float V     = V0[gidx];
  float dec   = decayB[gidx];
  float onemd = 1.f - dec;
  float thr   = thrB[gidx];

  // initial act into LDS
  {
    const float4* src = reinterpret_cast<const float4*>(act0 + (size_t)b * NN);
    float4* dst = reinterpret_cast<float4*>(alds);
    #pragma unroll
    for (int j = 0; j < 8; ++j) dst[tid + j * 256] = src[tid + j * 256];
  }
  __syncthreads();

  float inj = cc[((size_t)b * TT) * DD + (n >> 2)];

  for (int t = 0; t < TT; ++t) {
    // gather + dot over 64 random neighbors (LDS)
    float s0 = 0.f, s1 = 0.f, s2 = 0.f, s3 = 0.f;
    #pragma unroll
    for (int k = 0; k < KK; k += 4) {
      s0 = fmaf(alds[ad[k+0]], w[k+0], s0);
      s1 = fmaf(alds[ad[k+1]], w[k+1], s1);
      s2 = fmaf(alds[ad[k+2]], w[k+2], s2);
      s3 = fmaf(alds[ad[k+3]], w[k+3], s3);
    }
    float recv = (s0 + s1) + (s2 + s3) + inj;
    V = dec * V + onemd * recv;
    float x = V - thr;
    float a = 1.f / (1.f + expf(-x));

    const int pw = t & 1;
    if (t != TT - 1) {
      // publish slice value (coherent write-through), latency hidden below
      __hip_atomic_store(&actbuf[pw * (BS * NN) + gidx], a,
                         __ATOMIC_RELAXED, __HIP_MEMORY_SCOPE_AGENT);
    }

    // fused output: mean over groups of 4 neurons
    float p = a + __shfl_xor(a, 1);
    p = p + __shfl_xor(p, 2);
    if ((tid & 3) == 0)
      out[((size_t)b * TT + t) * DD + sl * 64 + (tid >> 2)] = 0.25f * p;

    if (t == TT - 1) break;

    // prefetch next step's injection while the publish store is in flight
    inj = cc[((size_t)b * TT + t + 1) * DD + (n >> 2)];

    // all this wave's vmem (publish store, out store, inj load) complete
    asm volatile("s_waitcnt vmcnt(0)" ::: "memory");
    __syncthreads();   // all waves of WG past their waitcnt
    if (tid == 0) {
      int* c = cnt + b;
      __hip_atomic_fetch_add(c, 1, __ATOMIC_RELAXED, __HIP_MEMORY_SCOPE_AGENT);
    }

    // wait for all 32 slices of this batch to have published step t
    {
      const int target = NSL * (t + 1);
      const int* c = cnt + b;
      for (;;) {
        int v = __hip_atomic_load(c, __ATOMIC_RELAXED, __HIP_MEMORY_SCOPE_AGENT);
        if (v >= target) break;
      }
    }
    asm volatile("" ::: "memory");

    // batched vectorized coherent reload of full batch act into LDS
    {
      const float* src = actbuf + pw * (BS * NN) + (size_t)b * NN;
      f32x4 vals[8];
      #pragma unroll
      for (int j = 0; j < 8; ++j) {
        const float* psrc = src + (tid << 2) + (j << 10);
        asm volatile("global_load_dwordx4 %0, %1, off sc0 sc1"
                     : "=v"(vals[j]) : "v"(psrc));
      }
      asm volatile("s_waitcnt vmcnt(0)" ::: "memory");
      f32x4* dst = reinterpret_cast<f32x4*>(alds);
      #pragma unroll
      for (int j = 0; j < 8; ++j) dst[tid + j * 256] = vals[j];
    }
    __syncthreads();
  }
}

extern "C" void kernel_launch(void* const* d_in, const int* in_sizes, int n_in,
                              void* d_out, int out_size, void* d_ws, size_t ws_size,
                              hipStream_t stream)
{
  const float* cc   = (const float*)d_in[0];
  const float* w1   = (const float*)d_in[1];
  const float* b1   = (const float*)d_in[2];
  const float* w2   = (const float*)d_in[3];
  const float* b2   = (const float*)d_in[4];
  const int*   conn = (const int*)d_in[5];
  const float* nid  = (const float*)d_in[6];
  const float* V0   = (const float*)d_in[7];
  const float* act0 = (const float*)d_in[8];
  const float* heb0 = (const float*)d_in[9];
  const float* dec0 = (const float*)d_in[10];
  const float* thr0 = (const float*)d_in[11];
  float* out = (float*)d_out;

  char* ws = (char*)d_ws;
  float* wconn  = (float*)ws;                               // 8*8192*64 f32 = 16 MB
  float* decayB = (float*)(ws + (size_t)BS * NN * KK * 4);  // 8*8192
  float* thrB   = decayB + BS * NN;                         // 8*8192
  float* actbuf = thrB + BS * NN;                           // 2*8*8192
  int*   cnt    = (int*)(actbuf + 2 * BS * NN);             // 8 counters

  hipMemsetAsync(cnt, 0, BS * sizeof(int), stream);

  dim3 gA(GG, BS);
  modulator_kernel<<<gA, 256, 0, stream>>>(w1, b1, w2, b2, act0, heb0, dec0, thr0,
                                           nid, wconn, decayB, thrB);
  scan_kernel<<<dim3(BS * NSL), 256, 0, stream>>>(cc, conn, V0, act0, wconn,
                                                  decayB, thrB, out, actbuf, cnt);
}

// Round 4
// 1598.499 us; speedup vs baseline: 3.1133x; 3.1133x over previous
//
#include <hip/hip_runtime.h>
#include <cstdint>
#include <cstddef>

#define BS 8
#define TT 256
#define DD 2048
#define NN 8192
#define KK 64
#define GG 512
#define GSZ 16
#define HH 64
#define MIN_ 69
#define MOUT_ 66
#define NSL 32     // slices per batch
#define SLN 256    // neurons per slice
#define NFL 128    // subflags per batch (32 slices x 4 waves)

typedef float f32x4 __attribute__((ext_vector_type(4)));

// ---------------- Phase A: modulator (runs once) ----------------
__global__ __launch_bounds__(256) void modulator_kernel(
    const float* __restrict__ w1, const float* __restrict__ b1,
    const float* __restrict__ w2, const float* __restrict__ b2,
    const float* __restrict__ act0, const float* __restrict__ heb0,
    const float* __restrict__ dec0, const float* __restrict__ thr0,
    const float* __restrict__ nid,
    float* __restrict__ wconn, float* __restrict__ decayB, float* __restrict__ thrB)
{
  const int g = blockIdx.x, b = blockIdx.y, tid = threadIdx.x;
  __shared__ float xs[GSZ][MIN_];
  __shared__ float hd[GSZ][HH];

  const int nbase = g * GSZ;
  // mod_in = [act(1), hebbian(64), decay(1), threshold(1), nid(2)]
  for (int j = tid; j < GSZ * KK; j += 256) {
    int s = j >> 6, k = j & 63;
    xs[s][1 + k] = heb0[((size_t)(b * NN + nbase + s)) * KK + k];
  }
  if (tid < GSZ) {
    int n = nbase + tid;
    xs[tid][0]  = act0[b * NN + n];
    xs[tid][65] = dec0[b * NN + n];
    xs[tid][66] = thr0[b * NN + n];
    xs[tid][67] = nid[2 * n];
    xs[tid][68] = nid[2 * n + 1];
  }
  __syncthreads();

  // hdn[s][h] = tanh(sum_i xs[s][i]*w1[g][i][h] + b1[g][h])
  for (int rep = 0; rep < 4; ++rep) {
    int t2 = tid + rep * 256;
    int s = t2 >> 6, h = t2 & 63;
    float acc = b1[g * HH + h];
    const float* w1g = w1 + (size_t)g * MIN_ * HH + h;
    for (int i = 0; i < MIN_; ++i) acc = fmaf(xs[s][i], w1g[(size_t)i * HH], acc);
    hd[s][h] = tanhf(acc);
  }
  __syncthreads();

  // out[s][o] = sum_h hd[s][h]*w2[g][h][o] + b2[g][o]
  for (int j = tid; j < GSZ * MOUT_; j += 256) {
    int s = j / MOUT_, o = j - s * MOUT_;
    float acc = b2[g * MOUT_ + o];
    const float* w2g = w2 + (size_t)g * HH * MOUT_ + o;
    for (int h = 0; h < HH; ++h) acc = fmaf(hd[s][h], w2g[(size_t)h * MOUT_], acc);
    int gidx = b * NN + nbase + s;
    if (o < KK)       wconn[(size_t)gidx * KK + o] = acc;
    else if (o == KK) decayB[gidx] = 1.f / (1.f + expf(-acc));
    else              thrB[gidx]   = acc;
  }
}

// ---------------- Phase B: 256-step recurrent scan ----------------
// 256 WGs (8 batches x 32 slices), 256 threads, 1 neuron/thread.
// Exchange via coherent (sc1) accesses: NO cache maintenance, NO barriers in
// the publish path. Per-WAVE subflags (value = completed step, monotone):
//   publish store -> s_waitcnt vmcnt(0) -> lane0 stores subflag = t+1.
// Readers poll all 128 subflags of their batch (2 coalesced loads/iter),
// then batched vectorized sc0sc1 reload into LDS, then one __syncthreads.
// WAR safety (double buffer): wave's subflag t+2 is ordered after its own
// step-t reload loads by its step-(t+1) vmcnt(0); a writer publishes into
// buffer pw at t+2 only after seeing ALL subflags >= t+2.
__global__ __launch_bounds__(256, 1) void scan_kernel(
    const float* __restrict__ cc, const int* __restrict__ conn,
    const float* __restrict__ V0, const float* __restrict__ act0,
    const float* __restrict__ wconn, const float* __restrict__ decayB,
    const float* __restrict__ thrB,
    float* __restrict__ out, float* actbuf, int* flags)
{
  const int tid  = threadIdx.x;
  const int lane = tid & 63;
  const int wv   = tid >> 6;
  const int b  = blockIdx.x >> 5;
  const int sl = blockIdx.x & 31;
  const int n    = sl * SLN + tid;
  const int gidx = b * NN + n;

  __shared__ float alds[NN];        // 32 KB: full act of batch b
  __shared__ float wl[KK * SLN];    // 64 KB: wl[k*256+tid] = w_conn[n][k] (transposed)

  // neighbor indices in VGPRs
  int ad[KK];
  {
    const int4* ir = reinterpret_cast<const int4*>(conn + (size_t)n * KK);
    #pragma unroll
    for (int j = 0; j < KK / 4; ++j) {
      int4 v = ir[j];
      ad[4*j+0] = v.x; ad[4*j+1] = v.y; ad[4*j+2] = v.z; ad[4*j+3] = v.w;
    }
  }
  // weights into LDS, transposed so gather reads are conflict-free
  {
    const float4* wr = reinterpret_cast<const float4*>(wconn + (size_t)gidx * KK);
    #pragma unroll
    for (int j = 0; j < KK / 4; ++j) {
      float4 v = wr[j];
      wl[(4*j+0) * SLN + tid] = v.x;
      wl[(4*j+1) * SLN + tid] = v.y;
      wl[(4*j+2) * SLN + tid] = v.z;
      wl[(4*j+3) * SLN + tid] = v.w;
    }
  }
  float V     = V0[gidx];
  float dec   = decayB[gidx];
  float onemd = 1.f - dec;
  float thr   = thrB[gidx];

  // initial act into LDS
  {
    const float4* src = reinterpret_cast<const float4*>(act0 + (size_t)b * NN);
    float4* dst = reinterpret_cast<float4*>(alds);
    #pragma unroll
    for (int j = 0; j < 8; ++j) dst[tid + j * 256] = src[tid + j * 256];
  }
  __syncthreads();

  float inj = cc[((size_t)b * TT) * DD + (n >> 2)];
  int* fl = flags + b * NFL;

  for (int t = 0; t < TT; ++t) {
    // gather + dot over 64 random neighbors (LDS only)
    float s0 = 0.f, s1 = 0.f, s2 = 0.f, s3 = 0.f;
    #pragma unroll
    for (int k = 0; k < KK; k += 4) {
      s0 = fmaf(alds[ad[k+0]], wl[(k+0) * SLN + tid], s0);
      s1 = fmaf(alds[ad[k+1]], wl[(k+1) * SLN + tid], s1);
      s2 = fmaf(alds[ad[k+2]], wl[(k+2) * SLN + tid], s2);
      s3 = fmaf(alds[ad[k+3]], wl[(k+3) * SLN + tid], s3);
    }
    float recv = (s0 + s1) + (s2 + s3) + inj;
    V = dec * V + onemd * recv;
    float x = V - thr;
    float a = 1.f / (1.f + expf(-x));

    // group-of-4 mean
    float p = a + __shfl_xor(a, 1);
    p = p + __shfl_xor(p, 2);

    if (t == TT - 1) {
      if ((tid & 3) == 0)
        out[((size_t)b * TT + t) * DD + sl * 64 + (tid >> 2)] = 0.25f * p;
      break;
    }

    const int pw = t & 1;
    // publish slice value (coherent write-through)
    __hip_atomic_store(&actbuf[pw * (BS * NN) + gidx], a,
                       __ATOMIC_RELAXED, __HIP_MEMORY_SCOPE_AGENT);
    // this wave's publish (and any older vmem) acked at the coherent point
    asm volatile("s_waitcnt vmcnt(0)" ::: "memory");
    // release: this wave completed step t
    if (lane == 0)
      __hip_atomic_store(&fl[sl * 4 + wv], t + 1,
                         __ATOMIC_RELAXED, __HIP_MEMORY_SCOPE_AGENT);

    // hidden under the poll: output store + next injection prefetch
    if ((tid & 3) == 0)
      out[((size_t)b * TT + t) * DD + sl * 64 + (tid >> 2)] = 0.25f * p;
    inj = cc[((size_t)b * TT + t + 1) * DD + (n >> 2)];

    // wait for all 128 subflags of this batch to reach t+1
    {
      const int tgt = t + 1;
      for (;;) {
        int v0 = __hip_atomic_load(fl + lane,      __ATOMIC_RELAXED, __HIP_MEMORY_SCOPE_AGENT);
        int v1 = __hip_atomic_load(fl + 64 + lane, __ATOMIC_RELAXED, __HIP_MEMORY_SCOPE_AGENT);
        if (__all(v0 >= tgt && v1 >= tgt)) break;
      }
    }
    asm volatile("" ::: "memory");

    // batched vectorized coherent reload of full batch act into LDS
    {
      const float* src = actbuf + pw * (BS * NN) + (size_t)b * NN;
      f32x4 vals[8];
      #pragma unroll
      for (int j = 0; j < 8; ++j) {
        const float* psrc = src + (tid << 2) + (j << 10);
        asm volatile("global_load_dwordx4 %0, %1, off sc0 sc1"
                     : "=v"(vals[j]) : "v"(psrc));
      }
      asm volatile("s_waitcnt vmcnt(0)" ::: "memory");
      f32x4* dst = reinterpret_cast<f32x4*>(alds);
      #pragma unroll
      for (int j = 0; j < 8; ++j) dst[tid + j * 256] = vals[j];
    }
    __syncthreads();
  }
}

extern "C" void kernel_launch(void* const* d_in, const int* in_sizes, int n_in,
                              void* d_out, int out_size, void* d_ws, size_t ws_size,
                              hipStream_t stream)
{
  const float* cc   = (const float*)d_in[0];
  const float* w1   = (const float*)d_in[1];
  const float* b1   = (const float*)d_in[2];
  const float* w2   = (const float*)d_in[3];
  const float* b2   = (const float*)d_in[4];
  const int*   conn = (const int*)d_in[5];
  const float* nid  = (const float*)d_in[6];
  const float* V0   = (const float*)d_in[7];
  const float* act0 = (const float*)d_in[8];
  const float* heb0 = (const float*)d_in[9];
  const float* dec0 = (const float*)d_in[10];
  const float* thr0 = (const float*)d_in[11];
  float* out = (float*)d_out;

  char* ws = (char*)d_ws;
  float* wconn  = (float*)ws;                               // 8*8192*64 f32 = 16 MB
  float* decayB = (float*)(ws + (size_t)BS * NN * KK * 4);  // 8*8192
  float* thrB   = decayB + BS * NN;                         // 8*8192
  float* actbuf = thrB + BS * NN;                           // 2*8*8192
  int*   flags  = (int*)(actbuf + 2 * BS * NN);             // 8*128 subflags

  hipMemsetAsync(flags, 0, BS * NFL * sizeof(int), stream);

  dim3 gA(GG, BS);
  modulator_kernel<<<gA, 256, 0, stream>>>(w1, b1, w2, b2, act0, heb0, dec0, thr0,
                                           nid, wconn, decayB, thrB);
  scan_kernel<<<dim3(BS * NSL), 256, 0, stream>>>(cc, conn, V0, act0, wconn,
                                                  decayB, thrB, out, actbuf, flags);
}

// Round 6
// 990.498 us; speedup vs baseline: 5.0244x; 1.6138x over previous
//
#include <hip/hip_runtime.h>
#include <hip/hip_fp16.h>
#include <cstdint>
#include <cstddef>

#define BS 8
#define TT 256
#define DD 2048
#define NN 8192
#define KK 64
#define GG 512
#define GSZ 16
#define HH 64
#define MIN_ 69
#define MOUT_ 66
#define NSL 32     // slices per batch
#define SLN 256    // neurons per slice

typedef float    f32x4 __attribute__((ext_vector_type(4)));
typedef uint32_t u32x4 __attribute__((ext_vector_type(4)));

// ---------------- Phase A: modulator (runs once) ----------------
__global__ __launch_bounds__(256) void modulator_kernel(
    const float* __restrict__ w1, const float* __restrict__ b1,
    const float* __restrict__ w2, const float* __restrict__ b2,
    const float* __restrict__ act0, const float* __restrict__ heb0,
    const float* __restrict__ dec0, const float* __restrict__ thr0,
    const float* __restrict__ nid,
    float* __restrict__ wconn, float* __restrict__ decayB, float* __restrict__ thrB)
{
  const int g = blockIdx.x, b = blockIdx.y, tid = threadIdx.x;
  __shared__ float xs[GSZ][MIN_];
  __shared__ float hd[GSZ][HH];

  const int nbase = g * GSZ;
  for (int j = tid; j < GSZ * KK; j += 256) {
    int s = j >> 6, k = j & 63;
    xs[s][1 + k] = heb0[((size_t)(b * NN + nbase + s)) * KK + k];
  }
  if (tid < GSZ) {
    int n = nbase + tid;
    xs[tid][0]  = act0[b * NN + n];
    xs[tid][65] = dec0[b * NN + n];
    xs[tid][66] = thr0[b * NN + n];
    xs[tid][67] = nid[2 * n];
    xs[tid][68] = nid[2 * n + 1];
  }
  __syncthreads();

  for (int rep = 0; rep < 4; ++rep) {
    int t2 = tid + rep * 256;
    int s = t2 >> 6, h = t2 & 63;
    float acc = b1[g * HH + h];
    const float* w1g = w1 + (size_t)g * MIN_ * HH + h;
    for (int i = 0; i < MIN_; ++i) acc = fmaf(xs[s][i], w1g[(size_t)i * HH], acc);
    hd[s][h] = tanhf(acc);
  }
  __syncthreads();

  for (int j = tid; j < GSZ * MOUT_; j += 256) {
    int s = j / MOUT_, o = j - s * MOUT_;
    float acc = b2[g * MOUT_ + o];
    const float* w2g = w2 + (size_t)g * HH * MOUT_ + o;
    for (int h = 0; h < HH; ++h) acc = fmaf(hd[s][h], w2g[(size_t)h * MOUT_], acc);
    int gidx = b * NN + nbase + s;
    if (o < KK)       wconn[(size_t)gidx * KK + o] = acc;
    else if (o == KK) decayB[gidx] = 1.f / (1.f + expf(-acc));
    else              thrB[gidx]   = acc;
  }
}

// ---------------- Phase B: 256-step recurrent scan ----------------
// 256 WGs (batch = blockIdx&7, slice = blockIdx>>3), 256 threads, 1 neuron/thread.
// Exchange payload: one dword per neuron = [tag=t+1 (hi16) | fp16 act (lo16)].
// Single-dword atomicity => data IS the flag: no publish-ack vmcnt, no flag
// store, no flag poll. Readers issue the 32KB batch reload and re-issue until
// all tags match t+1 exactly ("reload-as-poll").
// All exchange ops use the PROVEN sc0 sc1 bits (coherent at the device point;
// validated R2-R4). No XCD-local fast path (R5 post-mortem: sc0-only
// visibility unverified -> hang).
// WAR safety (double buffer, exact-match poll is live): a writer publishes
// tag t+3 into buffer pw only after its poll of pw^1 saw all tags t+2; a peer
// stores tag t+2 only after completing its tag-(t+1) poll of pw. Hence no
// word in pw is overwritten while any peer still polls it for t+1.
__global__ __launch_bounds__(256, 1) void scan_kernel(
    const float* __restrict__ cc, const int* __restrict__ conn,
    const float* __restrict__ V0, const float* __restrict__ act0,
    const float* __restrict__ wconn, const float* __restrict__ decayB,
    const float* __restrict__ thrB,
    float* __restrict__ out, uint32_t* actbuf)
{
  const int tid = threadIdx.x;
  const int b   = blockIdx.x & 7;   // batch (XCD-grouped under round-robin)
  const int sl  = blockIdx.x >> 3;  // slice 0..31
  const int n    = sl * SLN + tid;
  const int gidx = b * NN + n;

  __shared__ float alds[NN];        // 32 KB: full act of batch b (fp32)
  __shared__ float wl[KK * SLN];    // 64 KB: wl[k*256+tid] = w_conn[n][k]

  // neighbor indices in VGPRs
  int ad[KK];
  {
    const int4* ir = reinterpret_cast<const int4*>(conn + (size_t)n * KK);
    #pragma unroll
    for (int j = 0; j < KK / 4; ++j) {
      int4 v = ir[j];
      ad[4*j+0] = v.x; ad[4*j+1] = v.y; ad[4*j+2] = v.z; ad[4*j+3] = v.w;
    }
  }
  // weights into LDS, transposed (conflict-free stride-256 reads)
  {
    const float4* wr = reinterpret_cast<const float4*>(wconn + (size_t)gidx * KK);
    #pragma unroll
    for (int j = 0; j < KK / 4; ++j) {
      float4 v = wr[j];
      wl[(4*j+0) * SLN + tid] = v.x;
      wl[(4*j+1) * SLN + tid] = v.y;
      wl[(4*j+2) * SLN + tid] = v.z;
      wl[(4*j+3) * SLN + tid] = v.w;
    }
  }
  float V     = V0[gidx];
  float dec   = decayB[gidx];
  float onemd = 1.f - dec;
  float thr   = thrB[gidx];

  // initial act into LDS (exact fp32)
  {
    const float4* src = reinterpret_cast<const float4*>(act0 + (size_t)b * NN);
    float4* dst = reinterpret_cast<float4*>(alds);
    #pragma unroll
    for (int j = 0; j < 8; ++j) dst[tid + j * 256] = src[tid + j * 256];
  }
  __syncthreads();

  float inj = cc[((size_t)b * TT) * DD + (n >> 2)];

  for (int t = 0; t < TT; ++t) {
    // gather + dot over 64 random neighbors (LDS only)
    float s0 = 0.f, s1 = 0.f, s2 = 0.f, s3 = 0.f;
    #pragma unroll
    for (int k = 0; k < KK; k += 4) {
      s0 = fmaf(alds[ad[k+0]], wl[(k+0) * SLN + tid], s0);
      s1 = fmaf(alds[ad[k+1]], wl[(k+1) * SLN + tid], s1);
      s2 = fmaf(alds[ad[k+2]], wl[(k+2) * SLN + tid], s2);
      s3 = fmaf(alds[ad[k+3]], wl[(k+3) * SLN + tid], s3);
    }
    float recv = (s0 + s1) + (s2 + s3) + inj;
    V = dec * V + onemd * recv;
    float x = V - thr;
    float a = 1.f / (1.f + expf(-x));

    const int pw = t & 1;

    if (t != TT - 1) {
      // publish [tag | fp16(a)] — data and flag in one dword, device-coherent
      uint32_t word = ((uint32_t)(t + 1) << 16) |
                      (uint32_t)__half_as_ushort(__float2half_rn(a));
      uint32_t* dst = actbuf + (size_t)pw * (BS * NN) + gidx;
      asm volatile("global_store_dword %0, %1, off sc0 sc1"
                   :: "v"(dst), "v"(word) : "memory");
    }

    // group-of-4 mean (fp32 path for output)
    float p = a + __shfl_xor(a, 1);
    p = p + __shfl_xor(p, 2);
    if ((tid & 3) == 0)
      out[((size_t)b * TT + t) * DD + sl * 64 + (tid >> 2)] = 0.25f * p;

    if (t == TT - 1) break;

    // hidden under the reload-poll: next injection prefetch
    inj = cc[((size_t)b * TT + t + 1) * DD + (n >> 2)];

    // reload-as-poll: re-issue the coherent batch reload until all tags fresh
    const uint32_t* src = actbuf + (size_t)pw * (BS * NN) + (size_t)b * NN;
    const uint32_t expect = (uint32_t)(t + 1) << 16;
    u32x4 vals[8];
    for (;;) {
      #pragma unroll
      for (int j = 0; j < 8; ++j) {
        const uint32_t* p4 = src + (tid << 2) + (j << 10);
        asm volatile("global_load_dwordx4 %0, %1, off sc0 sc1"
                     : "=v"(vals[j]) : "v"(p4));
      }
      asm volatile("s_waitcnt vmcnt(0)" ::: "memory");
      uint32_t bad = 0;
      #pragma unroll
      for (int j = 0; j < 8; ++j) {
        bad |= (vals[j].x & 0xFFFF0000u) ^ expect;
        bad |= (vals[j].y & 0xFFFF0000u) ^ expect;
        bad |= (vals[j].z & 0xFFFF0000u) ^ expect;
        bad |= (vals[j].w & 0xFFFF0000u) ^ expect;
      }
      if (bad == 0) break;
    }
    // unpack fp16 payloads into LDS as fp32
    {
      const int base = (tid << 2);
      #pragma unroll
      for (int j = 0; j < 8; ++j) {
        int o = base + (j << 10);
        alds[o + 0] = __half2float(__ushort_as_half((unsigned short)(vals[j].x & 0xFFFFu)));
        alds[o + 1] = __half2float(__ushort_as_half((unsigned short)(vals[j].y & 0xFFFFu)));
        alds[o + 2] = __half2float(__ushort_as_half((unsigned short)(vals[j].z & 0xFFFFu)));
        alds[o + 3] = __half2float(__ushort_as_half((unsigned short)(vals[j].w & 0xFFFFu)));
      }
    }
    __syncthreads();
  }
}

extern "C" void kernel_launch(void* const* d_in, const int* in_sizes, int n_in,
                              void* d_out, int out_size, void* d_ws, size_t ws_size,
                              hipStream_t stream)
{
  const float* cc   = (const float*)d_in[0];
  const float* w1   = (const float*)d_in[1];
  const float* b1   = (const float*)d_in[2];
  const float* w2   = (const float*)d_in[3];
  const float* b2   = (const float*)d_in[4];
  const int*   conn = (const int*)d_in[5];
  const float* nid  = (const float*)d_in[6];
  const float* V0   = (const float*)d_in[7];
  const float* act0 = (const float*)d_in[8];
  const float* heb0 = (const float*)d_in[9];
  const float* dec0 = (const float*)d_in[10];
  const float* thr0 = (const float*)d_in[11];
  float* out = (float*)d_out;

  char* ws = (char*)d_ws;
  float*    wconn  = (float*)ws;                               // 16 MB
  float*    decayB = (float*)(ws + (size_t)BS * NN * KK * 4);  // 8*8192
  float*    thrB   = decayB + BS * NN;                         // 8*8192
  uint32_t* actbuf = (uint32_t*)(thrB + BS * NN);              // 2*8*8192 dwords

  // zero tags every launch (replay-deterministic; first poll expects tag 1)
  hipMemsetAsync(actbuf, 0, 2 * BS * NN * sizeof(uint32_t), stream);

  dim3 gA(GG, BS);
  modulator_kernel<<<gA, 256, 0, stream>>>(w1, b1, w2, b2, act0, heb0, dec0, thr0,
                                           nid, wconn, decayB, thrB);
  scan_kernel<<<dim3(BS * NSL), 256, 0, stream>>>(cc, conn, V0, act0, wconn,
                                                  decayB, thrB, out, actbuf);
}

// Round 7
// 920.799 us; speedup vs baseline: 5.4047x; 1.0757x over previous
//
#include <hip/hip_runtime.h>
#include <hip/hip_fp16.h>
#include <cstdint>
#include <cstddef>

#define BS 8
#define TT 256
#define DD 2048
#define NN 8192
#define KK 64
#define GG 512
#define GSZ 16
#define HH 64
#define MIN_ 69
#define MOUT_ 66
#define NSL 32     // slices per batch
#define SLN 256    // neurons per slice

typedef float    f32x4 __attribute__((ext_vector_type(4)));
typedef uint32_t u32x4 __attribute__((ext_vector_type(4)));

// ---------------- Phase A: modulator (runs once) ----------------
__global__ __launch_bounds__(256) void modulator_kernel(
    const float* __restrict__ w1, const float* __restrict__ b1,
    const float* __restrict__ w2, const float* __restrict__ b2,
    const float* __restrict__ act0, const float* __restrict__ heb0,
    const float* __restrict__ dec0, const float* __restrict__ thr0,
    const float* __restrict__ nid,
    float* __restrict__ wconn, float* __restrict__ decayB, float* __restrict__ thrB)
{
  const int g = blockIdx.x, b = blockIdx.y, tid = threadIdx.x;
  __shared__ float xs[GSZ][MIN_];
  __shared__ float hd[GSZ][HH];

  const int nbase = g * GSZ;
  for (int j = tid; j < GSZ * KK; j += 256) {
    int s = j >> 6, k = j & 63;
    xs[s][1 + k] = heb0[((size_t)(b * NN + nbase + s)) * KK + k];
  }
  if (tid < GSZ) {
    int n = nbase + tid;
    xs[tid][0]  = act0[b * NN + n];
    xs[tid][65] = dec0[b * NN + n];
    xs[tid][66] = thr0[b * NN + n];
    xs[tid][67] = nid[2 * n];
    xs[tid][68] = nid[2 * n + 1];
  }
  __syncthreads();

  for (int rep = 0; rep < 4; ++rep) {
    int t2 = tid + rep * 256;
    int s = t2 >> 6, h = t2 & 63;
    float acc = b1[g * HH + h];
    const float* w1g = w1 + (size_t)g * MIN_ * HH + h;
    for (int i = 0; i < MIN_; ++i) acc = fmaf(xs[s][i], w1g[(size_t)i * HH], acc);
    hd[s][h] = tanhf(acc);
  }
  __syncthreads();

  for (int j = tid; j < GSZ * MOUT_; j += 256) {
    int s = j / MOUT_, o = j - s * MOUT_;
    float acc = b2[g * MOUT_ + o];
    const float* w2g = w2 + (size_t)g * HH * MOUT_ + o;
    for (int h = 0; h < HH; ++h) acc = fmaf(hd[s][h], w2g[(size_t)h * MOUT_], acc);
    int gidx = b * NN + nbase + s;
    if (o < KK)       wconn[(size_t)gidx * KK + o] = acc;
    else if (o == KK) decayB[gidx] = 1.f / (1.f + expf(-acc));
    else              thrB[gidx]   = acc;
  }
}

// ---------------- Phase B: 256-step recurrent scan ----------------
// 256 WGs (batch = blockIdx&7, slice = blockIdx>>3), 256 threads, 1 neuron/thread.
// Exchange payload: one dword per neuron = [tag=t+1 (hi16) | fp16 act (lo16)].
// Data IS the flag (single-dword atomicity): no publish-ack vmcnt, no flag
// store/poll. Readers re-issue the 32KB coherent batch reload until all tags
// match t+1 exactly ("reload-as-poll"). All exchange ops: proven sc0 sc1 bits.
// WAR safety: writer publishes tag t+3 into pw only after its poll of pw^1
// saw all tags t+2; a peer stores t+2 only after completing its t+1 poll of
// pw => no word in pw overwritten while still being polled for t+1.
// R7: weights live in VGPRs (float4 x16 = 64 regs) instead of LDS — halves
// per-step LDS-pipe traffic. ad[] also VGPRs. LDS = act mirror only (32 KB).
__global__ __launch_bounds__(256, 1) void scan_kernel(
    const float* __restrict__ cc, const int* __restrict__ conn,
    const float* __restrict__ V0, const float* __restrict__ act0,
    const float* __restrict__ wconn, const float* __restrict__ decayB,
    const float* __restrict__ thrB,
    float* __restrict__ out, uint32_t* actbuf)
{
  const int tid = threadIdx.x;
  const int b   = blockIdx.x & 7;   // batch (XCD-grouped under round-robin)
  const int sl  = blockIdx.x >> 3;  // slice 0..31
  const int n    = sl * SLN + tid;
  const int gidx = b * NN + n;

  __shared__ float alds[NN];        // 32 KB: full act of batch b (fp32)

  // persistent per-thread state in VGPRs: 64 weights + 64 indices
  f32x4 w4[16];
  int   ad[KK];
  {
    const f32x4* wr = reinterpret_cast<const f32x4*>(wconn + (size_t)gidx * KK);
    #pragma unroll
    for (int j = 0; j < 16; ++j) w4[j] = wr[j];
    const int4* ir = reinterpret_cast<const int4*>(conn + (size_t)n * KK);
    #pragma unroll
    for (int j = 0; j < KK / 4; ++j) {
      int4 v = ir[j];
      ad[4*j+0] = v.x; ad[4*j+1] = v.y; ad[4*j+2] = v.z; ad[4*j+3] = v.w;
    }
  }
  float V     = V0[gidx];
  float dec   = decayB[gidx];
  float onemd = 1.f - dec;
  float thr   = thrB[gidx];

  // initial act into LDS (exact fp32)
  {
    const float4* src = reinterpret_cast<const float4*>(act0 + (size_t)b * NN);
    float4* dst = reinterpret_cast<float4*>(alds);
    #pragma unroll
    for (int j = 0; j < 8; ++j) dst[tid + j * 256] = src[tid + j * 256];
  }
  __syncthreads();

  float inj = cc[((size_t)b * TT) * DD + (n >> 2)];

  for (int t = 0; t < TT; ++t) {
    // gather + dot over 64 random neighbors (LDS reads: act only)
    float s0 = 0.f, s1 = 0.f, s2 = 0.f, s3 = 0.f;
    #pragma unroll
    for (int j = 0; j < 16; ++j) {
      s0 = fmaf(alds[ad[4*j+0]], w4[j].x, s0);
      s1 = fmaf(alds[ad[4*j+1]], w4[j].y, s1);
      s2 = fmaf(alds[ad[4*j+2]], w4[j].z, s2);
      s3 = fmaf(alds[ad[4*j+3]], w4[j].w, s3);
    }
    float recv = (s0 + s1) + (s2 + s3) + inj;
    V = dec * V + onemd * recv;
    float x = V - thr;
    float a = 1.f / (1.f + expf(-x));

    const int pw = t & 1;

    if (t != TT - 1) {
      // publish [tag | fp16(a)] — data and flag in one dword, device-coherent
      uint32_t word = ((uint32_t)(t + 1) << 16) |
                      (uint32_t)__half_as_ushort(__float2half_rn(a));
      uint32_t* dst = actbuf + (size_t)pw * (BS * NN) + gidx;
      asm volatile("global_store_dword %0, %1, off sc0 sc1"
                   :: "v"(dst), "v"(word) : "memory");
    }

    // group-of-4 mean (fp32 path for output)
    float p = a + __shfl_xor(a, 1);
    p = p + __shfl_xor(p, 2);
    if ((tid & 3) == 0)
      out[((size_t)b * TT + t) * DD + sl * 64 + (tid >> 2)] = 0.25f * p;

    if (t == TT - 1) break;

    // hidden under the reload-poll: next injection prefetch
    inj = cc[((size_t)b * TT + t + 1) * DD + (n >> 2)];

    // reload-as-poll: re-issue the coherent batch reload until all tags fresh
    const uint32_t* src = actbuf + (size_t)pw * (BS * NN) + (size_t)b * NN;
    const uint32_t expect = (uint32_t)(t + 1) << 16;
    u32x4 vals[8];
    for (;;) {
      #pragma unroll
      for (int j = 0; j < 8; ++j) {
        const uint32_t* p4 = src + (tid << 2) + (j << 10);
        asm volatile("global_load_dwordx4 %0, %1, off sc0 sc1"
                     : "=v"(vals[j]) : "v"(p4));
      }
      asm volatile("s_waitcnt vmcnt(0)" ::: "memory");
      uint32_t bad = 0;
      #pragma unroll
      for (int j = 0; j < 8; ++j) {
        bad |= (vals[j].x & 0xFFFF0000u) ^ expect;
        bad |= (vals[j].y & 0xFFFF0000u) ^ expect;
        bad |= (vals[j].z & 0xFFFF0000u) ^ expect;
        bad |= (vals[j].w & 0xFFFF0000u) ^ expect;
      }
      if (bad == 0) break;
    }
    // unpack fp16 payloads into LDS as fp32
    {
      const int base = (tid << 2);
      #pragma unroll
      for (int j = 0; j < 8; ++j) {
        int o = base + (j << 10);
        alds[o + 0] = __half2float(__ushort_as_half((unsigned short)(vals[j].x & 0xFFFFu)));
        alds[o + 1] = __half2float(__ushort_as_half((unsigned short)(vals[j].y & 0xFFFFu)));
        alds[o + 2] = __half2float(__ushort_as_half((unsigned short)(vals[j].z & 0xFFFFu)));
        alds[o + 3] = __half2float(__ushort_as_half((unsigned short)(vals[j].w & 0xFFFFu)));
      }
    }
    __syncthreads();
  }
}

extern "C" void kernel_launch(void* const* d_in, const int* in_sizes, int n_in,
                              void* d_out, int out_size, void* d_ws, size_t ws_size,
                              hipStream_t stream)
{
  const float* cc   = (const float*)d_in[0];
  const float* w1   = (const float*)d_in[1];
  const float* b1   = (const float*)d_in[2];
  const float* w2   = (const float*)d_in[3];
  const float* b2   = (const float*)d_in[4];
  const int*   conn = (const int*)d_in[5];
  const float* nid  = (const float*)d_in[6];
  const float* V0   = (const float*)d_in[7];
  const float* act0 = (const float*)d_in[8];
  const float* heb0 = (const float*)d_in[9];
  const float* dec0 = (const float*)d_in[10];
  const float* thr0 = (const float*)d_in[11];
  float* out = (float*)d_out;

  char* ws = (char*)d_ws;
  float*    wconn  = (float*)ws;                               // 16 MB
  float*    decayB = (float*)(ws + (size_t)BS * NN * KK * 4);  // 8*8192
  float*    thrB   = decayB + BS * NN;                         // 8*8192
  uint32_t* actbuf = (uint32_t*)(thrB + BS * NN);              // 2*8*8192 dwords

  // zero tags every launch (replay-deterministic; first poll expects tag 1)
  hipMemsetAsync(actbuf, 0, 2 * BS * NN * sizeof(uint32_t), stream);

  dim3 gA(GG, BS);
  modulator_kernel<<<gA, 256, 0, stream>>>(w1, b1, w2, b2, act0, heb0, dec0, thr0,
                                           nid, wconn, decayB, thrB);
  scan_kernel<<<dim3(BS * NSL), 256, 0, stream>>>(cc, conn, V0, act0, wconn,
                                                  decayB, thrB, out, actbuf);
}